// Round 3
// baseline (255.388 us; speedup 1.0000x reference)
//
#include <hip/hip_runtime.h>
#include <hip/hip_bf16.h>
#include <hip/hip_cooperative_groups.h>

namespace cg = cooperative_groups;

#define C_   512
#define HS   128
#define NN   10368   // 18*24*24 ; 324 k-steps of 32

typedef __bf16 bf16x8 __attribute__((ext_vector_type(8)));
typedef __bf16 bf16x4 __attribute__((ext_vector_type(4)));
typedef float  f32x4  __attribute__((ext_vector_type(4)));

// ---------------------------------------------------------------------------
// Single fused kernel, grid 256 x 512 (1 block/CU, 8 waves/CU), cooperative.
// phase == -1 : run all phases with grid.sync() between (cooperative launch).
// phase == p  : run only phase p, no grid sync (fallback: 4 normal launches).
//
// Phase A: units 0..1295  : 64x64 transpose-cast tiles -> xb [C][N], xbT [N][C]
//          units 1296..1359: Wi/Wj fp32 -> bf16
//          units 1360..1375: zero Mtf (fp32 [C][HS] accumulator)
// Phase B: wave-units 0..647   : fj[h][n]  = Wj@x + bj   (A=Wjb, Bt=xbT)
//          wave-units 648..1295: finm[n][h]= (Wi@x+bi)^T (A=xbT, Bt=Wib)
// Phase C: 2048 wave-units = 64 tiles(32c x 32h) x 32 K-chunks (~10 ksteps),
//          fp32 atomicAdd into Mtf[c][h] (device-scope).
// Phase D: 2592 wave-units (16 c0 x 162 n0), 32c x 64n tiles, K=128:
//          out[c][n] = feat[c][n] + scale * sum_h Mtf[c][h]*finm[n][h],
//          A-fragments built from fp32 Mtf in-register (cvt), scale post-MFMA.
// ---------------------------------------------------------------------------
__global__ __launch_bounds__(512, 2) void k_fused(
    const float* __restrict__ feat, const float* __restrict__ Wi,
    const float* __restrict__ bi,   const float* __restrict__ Wj,
    const float* __restrict__ bj,   const float* __restrict__ agg,
    float* __restrict__ out,
    __bf16* __restrict__ xb,  __bf16* __restrict__ xbT,
    __bf16* __restrict__ Wib, __bf16* __restrict__ Wjb,
    __bf16* __restrict__ fj,  __bf16* __restrict__ finm,
    float* __restrict__ Mtf,  int phase)
{
    cg::grid_group grid = cg::this_grid();
    __shared__ float tile[64][65];
    const int t    = threadIdx.x;
    const int gw   = blockIdx.x * 8 + (t >> 6);   // global wave id, 0..2047
    const int lane = t & 63;
    const int l16  = lane & 15;
    const int q    = lane >> 4;

    // ---------------- Phase A ----------------
    if (phase < 0 || phase == 0) {
        for (int u = blockIdx.x; u < 1376; u += 256) {
            if (u < 1296) {
                const int c0 = (u & 7) * 64, n0 = (u >> 3) * 64;
                const int tr = t >> 6, tn = t & 63;
                #pragma unroll
                for (int i = 0; i < 8; i++) {
                    int c = tr + i * 8;
                    float v = feat[(size_t)(c0 + c) * NN + n0 + tn];
                    xb[(size_t)(c0 + c) * NN + n0 + tn] = (__bf16)v;
                    tile[c][tn] = v;
                }
                __syncthreads();
                #pragma unroll
                for (int i = 0; i < 8; i++) {
                    int n = tr + i * 8;
                    xbT[(size_t)(n0 + n) * C_ + c0 + tn] = (__bf16)tile[tn][n];
                }
                __syncthreads();
            } else if (u < 1360) {
                const int b2 = u - 1296;
                const float* src = (b2 < 32) ? Wi : Wj;
                __bf16* dst      = (b2 < 32) ? Wib : Wjb;
                const int off = (b2 & 31) * 2048 + t * 4;
                float4 v = *(const float4*)(src + off);
                bf16x4 o;
                o[0] = (__bf16)v.x; o[1] = (__bf16)v.y;
                o[2] = (__bf16)v.z; o[3] = (__bf16)v.w;
                *(bf16x4*)(dst + off) = o;
            } else {
                const int j = u - 1360;
                f32x4 z = {0.f, 0.f, 0.f, 0.f};
                *(f32x4*)(Mtf + j * 4096 + t * 8)     = z;
                *(f32x4*)(Mtf + j * 4096 + t * 8 + 4) = z;
            }
        }
    }
    if (phase < 0) grid.sync();

    // ---------------- Phase B ----------------
    if (phase < 0 || phase == 1) {
        const int w = gw;
        if (w < 648) {
            const int h0 = (w & 3) * 32, n0 = (w >> 2) * 64;
            f32x4 acc[2][4] = {};
            for (int k = 0; k < 512; k += 32) {
                bf16x8 a[2], b[4];
                #pragma unroll
                for (int i = 0; i < 2; i++)
                    a[i] = *(const bf16x8*)(Wjb + (h0 + 16 * i + l16) * 512 + k + q * 8);
                #pragma unroll
                for (int tt = 0; tt < 4; tt++)
                    b[tt] = *(const bf16x8*)(xbT + (size_t)(n0 + 16 * tt + l16) * 512 + k + q * 8);
                #pragma unroll
                for (int i = 0; i < 2; i++)
                    #pragma unroll
                    for (int tt = 0; tt < 4; tt++)
                        acc[i][tt] = __builtin_amdgcn_mfma_f32_16x16x32_bf16(a[i], b[tt], acc[i][tt], 0, 0, 0);
            }
            #pragma unroll
            for (int i = 0; i < 2; i++)
                #pragma unroll
                for (int tt = 0; tt < 4; tt++)
                    #pragma unroll
                    for (int r = 0; r < 4; r++) {
                        int h = h0 + 16 * i + q * 4 + r;
                        int n = n0 + 16 * tt + l16;
                        fj[(size_t)h * NN + n] = (__bf16)(acc[i][tt][r] + bj[h]);
                    }
        } else if (w < 1296) {
            const int w2 = w - 648;
            const int n0 = (w2 >> 2) * 64, h0 = (w2 & 3) * 32;
            f32x4 acc[4][2] = {};
            for (int k = 0; k < 512; k += 32) {
                bf16x8 a[4], b[2];
                #pragma unroll
                for (int i = 0; i < 4; i++)
                    a[i] = *(const bf16x8*)(xbT + (size_t)(n0 + 16 * i + l16) * 512 + k + q * 8);
                #pragma unroll
                for (int tt = 0; tt < 2; tt++)
                    b[tt] = *(const bf16x8*)(Wib + (h0 + 16 * tt + l16) * 512 + k + q * 8);
                #pragma unroll
                for (int i = 0; i < 4; i++)
                    #pragma unroll
                    for (int tt = 0; tt < 2; tt++)
                        acc[i][tt] = __builtin_amdgcn_mfma_f32_16x16x32_bf16(a[i], b[tt], acc[i][tt], 0, 0, 0);
            }
            #pragma unroll
            for (int i = 0; i < 4; i++)
                #pragma unroll
                for (int tt = 0; tt < 2; tt++)
                    #pragma unroll
                    for (int r = 0; r < 4; r++) {
                        int n = n0 + 16 * i + q * 4 + r;
                        int h = h0 + 16 * tt + l16;
                        finm[(size_t)n * HS + h] = (__bf16)(acc[i][tt][r] + bi[h]);
                    }
        }
    }
    if (phase < 0) grid.sync();

    // ---------------- Phase C ----------------
    if (phase < 0 || phase == 2) {
        const int tl = gw & 63, chunk = gw >> 6;        // 64 tiles x 32 chunks
        const int c0 = (tl >> 2) * 32, h0 = (tl & 3) * 32;
        const int s0 = (chunk * 324) >> 5;
        const int s1 = ((chunk + 1) * 324) >> 5;
        f32x4 acc[2][2] = {};
        for (int s = s0; s < s1; s++) {
            int k = s * 32;
            bf16x8 a[2], bb[2];
            #pragma unroll
            for (int i = 0; i < 2; i++)
                a[i] = *(const bf16x8*)(xb + (size_t)(c0 + 16 * i + l16) * NN + k + q * 8);
            #pragma unroll
            for (int tt = 0; tt < 2; tt++)
                bb[tt] = *(const bf16x8*)(fj + (size_t)(h0 + 16 * tt + l16) * NN + k + q * 8);
            #pragma unroll
            for (int i = 0; i < 2; i++)
                #pragma unroll
                for (int tt = 0; tt < 2; tt++)
                    acc[i][tt] = __builtin_amdgcn_mfma_f32_16x16x32_bf16(a[i], bb[tt], acc[i][tt], 0, 0, 0);
        }
        #pragma unroll
        for (int i = 0; i < 2; i++)
            #pragma unroll
            for (int tt = 0; tt < 2; tt++)
                #pragma unroll
                for (int r = 0; r < 4; r++) {
                    int c = c0 + 16 * i + q * 4 + r;
                    int h = h0 + 16 * tt + l16;
                    atomicAdd(&Mtf[c * HS + h], acc[i][tt][r]);
                }
    }
    if (phase < 0) grid.sync();

    // ---------------- Phase D ----------------
    if (phase < 0 || phase == 3) {
        const float scale = agg[0] * (1.0f / (float)NN);
        for (int w = gw; w < 2592; w += 2048) {
            const int c0 = (w & 15) * 32, n0 = (w >> 4) * 64;
            f32x4 acc[2][4] = {};
            for (int k = 0; k < 128; k += 32) {
                bf16x8 a[2], b[4];
                #pragma unroll
                for (int i = 0; i < 2; i++) {
                    const int base = (c0 + 16 * i + l16) * HS + k + q * 8;
                    f32x4 s0 = *(const f32x4*)(Mtf + base);
                    f32x4 s1 = *(const f32x4*)(Mtf + base + 4);
                    #pragma unroll
                    for (int j = 0; j < 4; j++) {
                        a[i][j]     = (__bf16)s0[j];
                        a[i][4 + j] = (__bf16)s1[j];
                    }
                }
                #pragma unroll
                for (int tt = 0; tt < 4; tt++)
                    b[tt] = *(const bf16x8*)(finm + (size_t)(n0 + 16 * tt + l16) * HS + k + q * 8);
                #pragma unroll
                for (int i = 0; i < 2; i++)
                    #pragma unroll
                    for (int tt = 0; tt < 4; tt++)
                        acc[i][tt] = __builtin_amdgcn_mfma_f32_16x16x32_bf16(a[i], b[tt], acc[i][tt], 0, 0, 0);
            }
            #pragma unroll
            for (int i = 0; i < 2; i++)
                #pragma unroll
                for (int tt = 0; tt < 4; tt++)
                    #pragma unroll
                    for (int r = 0; r < 4; r++) {
                        int c = c0 + 16 * i + q * 4 + r;
                        int n = n0 + 16 * tt + l16;
                        size_t idx = (size_t)c * NN + n;
                        out[idx] = feat[idx] + scale * acc[i][tt][r];
                    }
        }
    }
}

// ---------------------------------------------------------------------------
// Workspace layout (bytes):
//   xb   @ 0          : 10,616,832
//   xbT  @ 10,616,832 : 10,616,832
//   Wib  @ 21,233,664 : 131,072
//   Wjb  @ 21,364,736 : 131,072
//   fj   @ 21,495,808 : 2,654,208
//   finm @ 24,150,016 : 2,654,208
//   Mtf  @ 26,804,224 : 262,144      total ~27.1 MB
// ---------------------------------------------------------------------------
extern "C" void kernel_launch(void* const* d_in, const int* in_sizes, int n_in,
                              void* d_out, int out_size, void* d_ws, size_t ws_size,
                              hipStream_t stream) {
    const float* feat = (const float*)d_in[0];
    const float* Wi   = (const float*)d_in[1];
    const float* bi   = (const float*)d_in[2];
    const float* Wj   = (const float*)d_in[3];
    const float* bj   = (const float*)d_in[4];
    const float* agg  = (const float*)d_in[5];
    float* out = (float*)d_out;

    char* ws = (char*)d_ws;
    __bf16* xb   = (__bf16*)(ws);
    __bf16* xbT  = (__bf16*)(ws + 10616832);
    __bf16* Wib  = (__bf16*)(ws + 21233664);
    __bf16* Wjb  = (__bf16*)(ws + 21364736);
    __bf16* fj   = (__bf16*)(ws + 21495808);
    __bf16* finm = (__bf16*)(ws + 24150016);
    float*  Mtf  = (float*) (ws + 26804224);

    int phase_all = -1;
    void* args[] = {
        (void*)&feat, (void*)&Wi, (void*)&bi, (void*)&Wj, (void*)&bj, (void*)&agg,
        (void*)&out, (void*)&xb, (void*)&xbT, (void*)&Wib, (void*)&Wjb,
        (void*)&fj, (void*)&finm, (void*)&Mtf, (void*)&phase_all
    };
    hipError_t err = hipLaunchCooperativeKernel((void*)k_fused, dim3(256), dim3(512),
                                                args, 0, stream);
    if (err != hipSuccess) {
        // Fallback: same kernel, one phase per launch, ordinary stream ordering.
        k_fused<<<256, 512, 0, stream>>>(feat, Wi, bi, Wj, bj, agg, out,
                                         xb, xbT, Wib, Wjb, fj, finm, Mtf, 0);
        k_fused<<<256, 512, 0, stream>>>(feat, Wi, bi, Wj, bj, agg, out,
                                         xb, xbT, Wib, Wjb, fj, finm, Mtf, 1);
        k_fused<<<256, 512, 0, stream>>>(feat, Wi, bi, Wj, bj, agg, out,
                                         xb, xbT, Wib, Wjb, fj, finm, Mtf, 2);
        k_fused<<<256, 512, 0, stream>>>(feat, Wi, bi, Wj, bj, agg, out,
                                         xb, xbT, Wib, Wjb, fj, finm, Mtf, 3);
    }
}

// Round 4
// 168.658 us; speedup vs baseline: 1.5142x; 1.5142x over previous
//
#include <hip/hip_runtime.h>
#include <hip/hip_bf16.h>

#define C_   512
#define HS   128
#define NN   10368   // 18*24*24 ; 324 k-steps of 32

typedef __bf16 bf16x8 __attribute__((ext_vector_type(8)));
typedef float  f32x4  __attribute__((ext_vector_type(4)));

// ---------------------------------------------------------------------------
// K1: transpose-cast feat fp32 [C][N] -> xbT bf16 [N][C] only.
//     (xb is gone: consumers of x-rows-along-n read feat fp32 directly.)
// ---------------------------------------------------------------------------
__global__ void k_transpose(const float* __restrict__ x, __bf16* __restrict__ xbT) {
    __shared__ float tile[64][65];
    const int c0 = blockIdx.x * 64, n0 = blockIdx.y * 64;
    const int t  = threadIdx.x;
    const int tr = t >> 6, tn = t & 63;
    #pragma unroll
    for (int i = 0; i < 16; i++) {
        int c = tr + i * 4;
        tile[c][tn] = x[(size_t)(c0 + c) * NN + n0 + tn];
    }
    __syncthreads();
    #pragma unroll
    for (int i = 0; i < 16; i++) {
        int n = tr + i * 4;
        xbT[(size_t)(n0 + n) * C_ + c0 + tn] = (__bf16)tile[tn][n];
    }
}

__device__ __forceinline__ bf16x8 load_f32x8_as_bf16(const float* __restrict__ p) {
    float4 v0 = *(const float4*)p;
    float4 v1 = *(const float4*)(p + 4);
    bf16x8 o;
    o[0] = (__bf16)v0.x; o[1] = (__bf16)v0.y; o[2] = (__bf16)v0.z; o[3] = (__bf16)v0.w;
    o[4] = (__bf16)v1.x; o[5] = (__bf16)v1.y; o[6] = (__bf16)v1.z; o[7] = (__bf16)v1.w;
    return o;
}

// ---------------------------------------------------------------------------
// K2 (fused G1+G2): 1296 waves. Weights read as fp32 + in-register cvt.
//   waves [0,648):   fj[h][n]   = sum_c Wj[h][c]*x[c][n] + bj[h]
//   waves [648,1296) finm[n][h] = sum_c x[c][n]*Wi[h][c] + bi[h]
// ---------------------------------------------------------------------------
__global__ void k_gemm12(const __bf16* __restrict__ xbT,
                         const float* __restrict__ Wi, const float* __restrict__ Wj,
                         const float* __restrict__ bi, const float* __restrict__ bj,
                         __bf16* __restrict__ fj, __bf16* __restrict__ finm) {
    const int w    = blockIdx.x * 4 + (threadIdx.x >> 6);
    const int lane = threadIdx.x & 63;
    const int l16  = lane & 15;
    const int q    = lane >> 4;
    if (w < 648) {
        const int h0 = (w & 3) * 32, n0 = (w >> 2) * 64;
        f32x4 acc[2][4] = {};
        for (int k = 0; k < 512; k += 32) {
            bf16x8 a[2], b[4];
            #pragma unroll
            for (int i = 0; i < 2; i++)
                a[i] = load_f32x8_as_bf16(Wj + (h0 + 16 * i + l16) * 512 + k + q * 8);
            #pragma unroll
            for (int tt = 0; tt < 4; tt++)
                b[tt] = *(const bf16x8*)(xbT + (size_t)(n0 + 16 * tt + l16) * 512 + k + q * 8);
            #pragma unroll
            for (int i = 0; i < 2; i++)
                #pragma unroll
                for (int tt = 0; tt < 4; tt++)
                    acc[i][tt] = __builtin_amdgcn_mfma_f32_16x16x32_bf16(a[i], b[tt], acc[i][tt], 0, 0, 0);
        }
        #pragma unroll
        for (int i = 0; i < 2; i++)
            #pragma unroll
            for (int tt = 0; tt < 4; tt++)
                #pragma unroll
                for (int r = 0; r < 4; r++) {
                    int h = h0 + 16 * i + q * 4 + r;
                    int n = n0 + 16 * tt + l16;
                    fj[(size_t)h * NN + n] = (__bf16)(acc[i][tt][r] + bj[h]);
                }
    } else {
        const int w2 = w - 648;
        const int n0 = (w2 >> 2) * 64, h0 = (w2 & 3) * 32;
        f32x4 acc[4][2] = {};
        for (int k = 0; k < 512; k += 32) {
            bf16x8 a[4], b[2];
            #pragma unroll
            for (int i = 0; i < 4; i++)
                a[i] = *(const bf16x8*)(xbT + (size_t)(n0 + 16 * i + l16) * 512 + k + q * 8);
            #pragma unroll
            for (int tt = 0; tt < 2; tt++)
                b[tt] = load_f32x8_as_bf16(Wi + (h0 + 16 * tt + l16) * 512 + k + q * 8);
            #pragma unroll
            for (int i = 0; i < 4; i++)
                #pragma unroll
                for (int tt = 0; tt < 2; tt++)
                    acc[i][tt] = __builtin_amdgcn_mfma_f32_16x16x32_bf16(a[i], b[tt], acc[i][tt], 0, 0, 0);
        }
        #pragma unroll
        for (int i = 0; i < 4; i++)
            #pragma unroll
            for (int tt = 0; tt < 2; tt++)
                #pragma unroll
                for (int r = 0; r < 4; r++) {
                    int n = n0 + 16 * i + q * 4 + r;
                    int h = h0 + 16 * tt + l16;
                    finm[(size_t)n * HS + h] = (__bf16)(acc[i][tt][r] + bi[h]);
                }
    }
}

// ---------------------------------------------------------------------------
// K3 (G3): Mtb[c][h] = bf16( sum_n feat[c][n] * fj[h][n] )   (raw, unscaled)
//   128 blocks x 512 thr: one 16c x 32h tile per block, K=324 steps split
//   8 ways across waves, LDS reduce, direct bf16 store. No atomics, no zero.
//   A-fragments read feat fp32 directly (same layout as xb) + cvt.
// ---------------------------------------------------------------------------
__global__ void k_gemm3(const float* __restrict__ feat, const __bf16* __restrict__ fj,
                        __bf16* __restrict__ Mtb) {
    __shared__ float red[8][64][9];
    const int b    = blockIdx.x;          // 0..127
    const int t    = threadIdx.x;         // 0..511
    const int wv   = t >> 6;              // 0..7
    const int lane = t & 63;
    const int l16  = lane & 15;
    const int q    = lane >> 4;
    const int c0 = (b >> 2) * 16, h0 = (b & 3) * 32;
    const int s0 = (wv * 324) >> 3;
    const int s1 = ((wv + 1) * 324) >> 3;
    f32x4 acc[2] = {};
    for (int s = s0; s < s1; s++) {
        int k = s * 32;
        bf16x8 a = load_f32x8_as_bf16(feat + (size_t)(c0 + l16) * NN + k + q * 8);
        bf16x8 b0 = *(const bf16x8*)(fj + (size_t)(h0 + l16) * NN + k + q * 8);
        bf16x8 b1 = *(const bf16x8*)(fj + (size_t)(h0 + 16 + l16) * NN + k + q * 8);
        acc[0] = __builtin_amdgcn_mfma_f32_16x16x32_bf16(a, b0, acc[0], 0, 0, 0);
        acc[1] = __builtin_amdgcn_mfma_f32_16x16x32_bf16(a, b1, acc[1], 0, 0, 0);
    }
    #pragma unroll
    for (int tt = 0; tt < 2; tt++)
        #pragma unroll
        for (int r = 0; r < 4; r++)
            red[wv][lane][tt * 4 + r] = acc[tt][r];
    __syncthreads();
    // 512 threads each reduce one (lane,j) entry across the 8 waves.
    const int lane_e = t >> 3, j = t & 7;
    float s = red[0][lane_e][j];
    #pragma unroll
    for (int v = 1; v < 8; v++) s += red[v][lane_e][j];
    const int qe = lane_e >> 4, le = lane_e & 15;
    const int tt = j >> 2, r = j & 3;
    const int c = c0 + qe * 4 + r;
    const int h = h0 + 16 * tt + le;
    Mtb[c * HS + h] = (__bf16)s;
}

// ---------------------------------------------------------------------------
// K4 (G4 + scale + residual):
//   out[c][n] = feat[c][n] + (agg/N) * sum_h Mtb[c][h] * finm[n][h]
//   Lean R1 form: A = Mtb bf16 [512][128], Bt = finm bf16 [NN][128], K=128.
// ---------------------------------------------------------------------------
__global__ void k_gemm4(const __bf16* __restrict__ Mtb, const __bf16* __restrict__ finm,
                        const float* __restrict__ feat, const float* __restrict__ agg,
                        float* __restrict__ out) {
    const int w    = blockIdx.x * 4 + (threadIdx.x >> 6);   // 0..2591
    const int lane = threadIdx.x & 63;
    const int l16  = lane & 15;
    const int q    = lane >> 4;
    const int c0 = (w & 15) * 32, n0 = (w >> 4) * 64;
    const float scale = agg[0] * (1.0f / (float)NN);
    f32x4 acc[2][4] = {};
    for (int k = 0; k < 128; k += 32) {
        bf16x8 a[2], b[4];
        #pragma unroll
        for (int i = 0; i < 2; i++)
            a[i] = *(const bf16x8*)(Mtb + (c0 + 16 * i + l16) * HS + k + q * 8);
        #pragma unroll
        for (int tt = 0; tt < 4; tt++)
            b[tt] = *(const bf16x8*)(finm + (size_t)(n0 + 16 * tt + l16) * HS + k + q * 8);
        #pragma unroll
        for (int i = 0; i < 2; i++)
            #pragma unroll
            for (int tt = 0; tt < 4; tt++)
                acc[i][tt] = __builtin_amdgcn_mfma_f32_16x16x32_bf16(a[i], b[tt], acc[i][tt], 0, 0, 0);
    }
    #pragma unroll
    for (int i = 0; i < 2; i++)
        #pragma unroll
        for (int tt = 0; tt < 4; tt++)
            #pragma unroll
            for (int r = 0; r < 4; r++) {
                int c = c0 + 16 * i + q * 4 + r;
                int n = n0 + 16 * tt + l16;
                size_t idx = (size_t)c * NN + n;
                out[idx] = feat[idx] + scale * acc[i][tt][r];
            }
}

// ---------------------------------------------------------------------------
// Workspace layout (bytes):
//   xbT  @ 0          : 10,616,832
//   fj   @ 10,616,832 : 2,654,208
//   finm @ 13,271,040 : 2,654,208
//   Mtb  @ 15,925,248 : 131,072       total ~16.1 MB
// ---------------------------------------------------------------------------
extern "C" void kernel_launch(void* const* d_in, const int* in_sizes, int n_in,
                              void* d_out, int out_size, void* d_ws, size_t ws_size,
                              hipStream_t stream) {
    const float* feat = (const float*)d_in[0];
    const float* Wi   = (const float*)d_in[1];
    const float* bi   = (const float*)d_in[2];
    const float* Wj   = (const float*)d_in[3];
    const float* bj   = (const float*)d_in[4];
    const float* agg  = (const float*)d_in[5];
    float* out = (float*)d_out;

    char* ws = (char*)d_ws;
    __bf16* xbT  = (__bf16*)(ws);
    __bf16* fj   = (__bf16*)(ws + 10616832);
    __bf16* finm = (__bf16*)(ws + 13271040);
    __bf16* Mtb  = (__bf16*)(ws + 15925248);

    k_transpose<<<dim3(8, 162), 256, 0, stream>>>(feat, xbT);
    k_gemm12<<<324, 256, 0, stream>>>(xbT, Wi, Wj, bi, bj, fj, finm);
    k_gemm3<<<128, 512, 0, stream>>>(feat, fj, Mtb);
    k_gemm4<<<648, 256, 0, stream>>>(Mtb, finm, feat, agg, out);
}

// Round 5
// 145.887 us; speedup vs baseline: 1.7506x; 1.1561x over previous
//
#include <hip/hip_runtime.h>
#include <hip/hip_bf16.h>

#define C_   512
#define HS   128
#define NN   10368   // 18*24*24 ; 324 k-steps of 32

typedef __bf16 bf16x8 __attribute__((ext_vector_type(8)));
typedef float  f32x4  __attribute__((ext_vector_type(4)));

// ---------------------------------------------------------------------------
// K1: blocks [0,1296): transpose-cast feat fp32 [C][N] -> xbT bf16 [N][C].
//     blocks [1296,1312): zero Mtf (fp32 [C][HS]) -- feeds gemm3's atomics.
// ---------------------------------------------------------------------------
__global__ void k_transpose(const float* __restrict__ x, __bf16* __restrict__ xbT,
                            float* __restrict__ Mtf) {
    const int b = blockIdx.x;
    const int t = threadIdx.x;
    if (b < 1296) {
        __shared__ float tile[64][65];
        const int c0 = (b & 7) * 64, n0 = (b >> 3) * 64;
        const int tr = t >> 6, tn = t & 63;
        #pragma unroll
        for (int i = 0; i < 16; i++) {
            int c = tr + i * 4;
            tile[c][tn] = x[(size_t)(c0 + c) * NN + n0 + tn];
        }
        __syncthreads();
        #pragma unroll
        for (int i = 0; i < 16; i++) {
            int n = tr + i * 4;
            xbT[(size_t)(n0 + n) * C_ + c0 + tn] = (__bf16)tile[tn][n];
        }
    } else {
        const int j = b - 1296;                 // 0..15, 4096 floats each
        f32x4 z = {0.f, 0.f, 0.f, 0.f};
        float* p = Mtf + j * 4096 + t * 16;
        *(f32x4*)(p)      = z;
        *(f32x4*)(p + 4)  = z;
        *(f32x4*)(p + 8)  = z;
        *(f32x4*)(p + 12) = z;
    }
}

__device__ __forceinline__ bf16x8 load_f32x8_as_bf16(const float* __restrict__ p) {
    float4 v0 = *(const float4*)p;
    float4 v1 = *(const float4*)(p + 4);
    bf16x8 o;
    o[0] = (__bf16)v0.x; o[1] = (__bf16)v0.y; o[2] = (__bf16)v0.z; o[3] = (__bf16)v0.w;
    o[4] = (__bf16)v1.x; o[5] = (__bf16)v1.y; o[6] = (__bf16)v1.z; o[7] = (__bf16)v1.w;
    return o;
}

// ---------------------------------------------------------------------------
// K2 (fused G1+G2): 1296 waves. Weights read fp32 + in-register cvt.
//   waves [0,648):   fj[h][n]   = sum_c Wj[h][c]*x[c][n] + bj[h]
//   waves [648,1296) finm[n][h] = sum_c x[c][n]*Wi[h][c] + bi[h]
// ---------------------------------------------------------------------------
__global__ void k_gemm12(const __bf16* __restrict__ xbT,
                         const float* __restrict__ Wi, const float* __restrict__ Wj,
                         const float* __restrict__ bi, const float* __restrict__ bj,
                         __bf16* __restrict__ fj, __bf16* __restrict__ finm) {
    const int w    = blockIdx.x * 4 + (threadIdx.x >> 6);
    const int lane = threadIdx.x & 63;
    const int l16  = lane & 15;
    const int q    = lane >> 4;
    if (w < 648) {
        const int h0 = (w & 3) * 32, n0 = (w >> 2) * 64;
        f32x4 acc[2][4] = {};
        for (int k = 0; k < 512; k += 32) {
            bf16x8 a[2], b[4];
            #pragma unroll
            for (int i = 0; i < 2; i++)
                a[i] = load_f32x8_as_bf16(Wj + (h0 + 16 * i + l16) * 512 + k + q * 8);
            #pragma unroll
            for (int tt = 0; tt < 4; tt++)
                b[tt] = *(const bf16x8*)(xbT + (size_t)(n0 + 16 * tt + l16) * 512 + k + q * 8);
            #pragma unroll
            for (int i = 0; i < 2; i++)
                #pragma unroll
                for (int tt = 0; tt < 4; tt++)
                    acc[i][tt] = __builtin_amdgcn_mfma_f32_16x16x32_bf16(a[i], b[tt], acc[i][tt], 0, 0, 0);
        }
        #pragma unroll
        for (int i = 0; i < 2; i++)
            #pragma unroll
            for (int tt = 0; tt < 4; tt++)
                #pragma unroll
                for (int r = 0; r < 4; r++) {
                    int h = h0 + 16 * i + q * 4 + r;
                    int n = n0 + 16 * tt + l16;
                    fj[(size_t)h * NN + n] = (__bf16)(acc[i][tt][r] + bj[h]);
                }
    } else {
        const int w2 = w - 648;
        const int n0 = (w2 >> 2) * 64, h0 = (w2 & 3) * 32;
        f32x4 acc[4][2] = {};
        for (int k = 0; k < 512; k += 32) {
            bf16x8 a[4], b[2];
            #pragma unroll
            for (int i = 0; i < 4; i++)
                a[i] = *(const bf16x8*)(xbT + (size_t)(n0 + 16 * i + l16) * 512 + k + q * 8);
            #pragma unroll
            for (int tt = 0; tt < 2; tt++)
                b[tt] = load_f32x8_as_bf16(Wi + (h0 + 16 * tt + l16) * 512 + k + q * 8);
            #pragma unroll
            for (int i = 0; i < 4; i++)
                #pragma unroll
                for (int tt = 0; tt < 2; tt++)
                    acc[i][tt] = __builtin_amdgcn_mfma_f32_16x16x32_bf16(a[i], b[tt], acc[i][tt], 0, 0, 0);
        }
        #pragma unroll
        for (int i = 0; i < 4; i++)
            #pragma unroll
            for (int tt = 0; tt < 2; tt++)
                #pragma unroll
                for (int r = 0; r < 4; r++) {
                    int n = n0 + 16 * i + q * 4 + r;
                    int h = h0 + 16 * tt + l16;
                    finm[(size_t)n * HS + h] = (__bf16)(acc[i][tt][r] + bi[h]);
                }
    }
}

// ---------------------------------------------------------------------------
// K3 (G3): Mtf[c][h] += sum_n feat[c][n] * fj[h][n]   (fp32 atomics)
//   512 blocks x 256 thr (2 blocks/CU, 8 waves/CU — full chip):
//   64 tiles (32c x 32h) x 8 chunk-groups; the 4 waves of a block take 4
//   adjacent K-chunks (~10 ksteps each), LDS-reduce, 8-contender atomicAdd.
//   A-fragments read feat fp32 directly + in-register cvt.
// ---------------------------------------------------------------------------
__global__ void k_gemm3(const float* __restrict__ feat, const __bf16* __restrict__ fj,
                        float* __restrict__ Mtf) {
    __shared__ float red[4][64][17];
    const int b    = blockIdx.x;          // 0..511
    const int t    = threadIdx.x;         // 0..255
    const int v    = t >> 6;              // wave 0..3
    const int lane = t & 63;
    const int l16  = lane & 15;
    const int q    = lane >> 4;
    const int tile = b & 63, g = b >> 6;  // 64 tiles x 8 groups
    const int c0 = (tile >> 2) * 32, h0 = (tile & 3) * 32;
    const int chunk = g * 4 + v;          // 0..31
    const int s0 = (chunk * 324) >> 5;
    const int s1 = ((chunk + 1) * 324) >> 5;
    f32x4 acc[2][2] = {};
    for (int s = s0; s < s1; s++) {
        int k = s * 32;
        bf16x8 a[2], bb[2];
        #pragma unroll
        for (int i = 0; i < 2; i++)
            a[i] = load_f32x8_as_bf16(feat + (size_t)(c0 + 16 * i + l16) * NN + k + q * 8);
        #pragma unroll
        for (int tt = 0; tt < 2; tt++)
            bb[tt] = *(const bf16x8*)(fj + (size_t)(h0 + 16 * tt + l16) * NN + k + q * 8);
        #pragma unroll
        for (int i = 0; i < 2; i++)
            #pragma unroll
            for (int tt = 0; tt < 2; tt++)
                acc[i][tt] = __builtin_amdgcn_mfma_f32_16x16x32_bf16(a[i], bb[tt], acc[i][tt], 0, 0, 0);
    }
    #pragma unroll
    for (int i = 0; i < 2; i++)
        #pragma unroll
        for (int tt = 0; tt < 2; tt++)
            #pragma unroll
            for (int r = 0; r < 4; r++)
                red[v][lane][i * 8 + tt * 4 + r] = acc[i][tt][r];
    __syncthreads();
    // 256 threads x 4 entries: reduce across the 4 waves, one atomic each.
    #pragma unroll
    for (int u = 0; u < 4; u++) {
        const int idx = t * 4 + u;        // 0..1023
        const int lane_e = idx >> 4, j = idx & 15;
        float s = red[0][lane_e][j] + red[1][lane_e][j]
                + red[2][lane_e][j] + red[3][lane_e][j];
        const int i = j >> 3, tt = (j >> 2) & 1, r = j & 3;
        const int qe = lane_e >> 4, le = lane_e & 15;
        const int c = c0 + 16 * i + qe * 4 + r;
        const int h = h0 + 16 * tt + le;
        atomicAdd(&Mtf[c * HS + h], s);
    }
}

// ---------------------------------------------------------------------------
// K4 (G4 + scale + residual):
//   out[c][n] = feat[c][n] + (agg/N) * sum_h Mtf[c][h] * finm[n][h]
//   A-fragments from fp32 Mtf (2x f32x4 + cvt — thin), Bt = finm bf16, K=128.
// ---------------------------------------------------------------------------
__global__ void k_gemm4(const float* __restrict__ Mtf, const __bf16* __restrict__ finm,
                        const float* __restrict__ feat, const float* __restrict__ agg,
                        float* __restrict__ out) {
    const int w    = blockIdx.x * 4 + (threadIdx.x >> 6);   // 0..2591
    const int lane = threadIdx.x & 63;
    const int l16  = lane & 15;
    const int q    = lane >> 4;
    const int c0 = (w & 15) * 32, n0 = (w >> 4) * 64;
    const float scale = agg[0] * (1.0f / (float)NN);
    f32x4 acc[2][4] = {};
    for (int k = 0; k < 128; k += 32) {
        bf16x8 a[2], b[4];
        #pragma unroll
        for (int i = 0; i < 2; i++)
            a[i] = load_f32x8_as_bf16(Mtf + (c0 + 16 * i + l16) * HS + k + q * 8);
        #pragma unroll
        for (int tt = 0; tt < 4; tt++)
            b[tt] = *(const bf16x8*)(finm + (size_t)(n0 + 16 * tt + l16) * HS + k + q * 8);
        #pragma unroll
        for (int i = 0; i < 2; i++)
            #pragma unroll
            for (int tt = 0; tt < 4; tt++)
                acc[i][tt] = __builtin_amdgcn_mfma_f32_16x16x32_bf16(a[i], b[tt], acc[i][tt], 0, 0, 0);
    }
    #pragma unroll
    for (int i = 0; i < 2; i++)
        #pragma unroll
        for (int tt = 0; tt < 4; tt++)
            #pragma unroll
            for (int r = 0; r < 4; r++) {
                int c = c0 + 16 * i + q * 4 + r;
                int n = n0 + 16 * tt + l16;
                size_t idx = (size_t)c * NN + n;
                out[idx] = feat[idx] + scale * acc[i][tt][r];
            }
}

// ---------------------------------------------------------------------------
// Workspace layout (bytes):
//   xbT  @ 0          : 10,616,832
//   fj   @ 10,616,832 : 2,654,208
//   finm @ 13,271,040 : 2,654,208
//   Mtf  @ 15,925,248 : 262,144       total ~16.2 MB
// ---------------------------------------------------------------------------
extern "C" void kernel_launch(void* const* d_in, const int* in_sizes, int n_in,
                              void* d_out, int out_size, void* d_ws, size_t ws_size,
                              hipStream_t stream) {
    const float* feat = (const float*)d_in[0];
    const float* Wi   = (const float*)d_in[1];
    const float* bi   = (const float*)d_in[2];
    const float* Wj   = (const float*)d_in[3];
    const float* bj   = (const float*)d_in[4];
    const float* agg  = (const float*)d_in[5];
    float* out = (float*)d_out;

    char* ws = (char*)d_ws;
    __bf16* xbT  = (__bf16*)(ws);
    __bf16* fj   = (__bf16*)(ws + 10616832);
    __bf16* finm = (__bf16*)(ws + 13271040);
    float*  Mtf  = (float*) (ws + 15925248);

    k_transpose<<<1312, 256, 0, stream>>>(feat, xbT, Mtf);
    k_gemm12<<<324, 256, 0, stream>>>(xbT, Wi, Wj, bi, bj, fj, finm);
    k_gemm3<<<512, 256, 0, stream>>>(feat, fj, Mtf);
    k_gemm4<<<648, 256, 0, stream>>>(Mtf, finm, feat, agg, out);
}

// Round 6
// 139.131 us; speedup vs baseline: 1.8356x; 1.0486x over previous
//
#include <hip/hip_runtime.h>
#include <hip/hip_bf16.h>

#define C_   512
#define HS   128
#define NN   10368   // 18*24*24 ; 324 k-steps of 32

typedef __bf16 bf16x8 __attribute__((ext_vector_type(8)));
typedef __bf16 bf16x2 __attribute__((ext_vector_type(2)));
typedef float  f32x4  __attribute__((ext_vector_type(4)));

__device__ __forceinline__ bf16x8 load_f32x8_as_bf16(const float* __restrict__ p) {
    float4 v0 = *(const float4*)p;
    float4 v1 = *(const float4*)(p + 4);
    bf16x8 o;
    o[0] = (__bf16)v0.x; o[1] = (__bf16)v0.y; o[2] = (__bf16)v0.z; o[3] = (__bf16)v0.w;
    o[4] = (__bf16)v1.x; o[5] = (__bf16)v1.y; o[6] = (__bf16)v1.z; o[7] = (__bf16)v1.w;
    return o;
}

// ---------------------------------------------------------------------------
// K12 (fused transpose + G1 + G2):
//   blocks [0,324): per block, n-tile of 32:
//     stage: read feat fp32 [512c][32n], write xb bf16 (byproduct for K3),
//            store transposed bf16 tile xt[32n][512c] in LDS (stride 520:
//            rows 16B-aligned for ds_read_b128; <=4-way bank aliasing).
//     compute (4 waves, wave w: h0 = 32w):
//       fj[h][n]   = sum_c Wj[h][c]*x[c][n] + bj[h]   (A=Wj fp32+cvt, B=xt)
//       finm[n][h] = sum_c x[c][n]*Wi[h][c] + bi[h]   (A=xt, B=Wi fp32+cvt)
//       -- the xt fragment is loaded ONCE and reused as fj's B and finm's A.
//   blocks [324,340): zero Mtf (fp32 [C][HS]) for K3's atomics.
// ---------------------------------------------------------------------------
__global__ void k_fused12(const float* __restrict__ feat,
                          const float* __restrict__ Wi, const float* __restrict__ Wj,
                          const float* __restrict__ bi, const float* __restrict__ bj,
                          __bf16* __restrict__ xb, __bf16* __restrict__ fj,
                          __bf16* __restrict__ finm, float* __restrict__ Mtf) {
    const int b = blockIdx.x;
    const int t = threadIdx.x;
    if (b >= 324) {                       // zero Mtf: 16 blocks x 256 thr x 16 floats
        const int j = b - 324;
        f32x4 z = {0.f, 0.f, 0.f, 0.f};
        float* p = Mtf + j * 4096 + t * 16;
        *(f32x4*)(p) = z; *(f32x4*)(p + 4) = z;
        *(f32x4*)(p + 8) = z; *(f32x4*)(p + 12) = z;
        return;
    }
    __shared__ __bf16 xt[32][520];
    const int n0 = b * 32;
    // ---- stage: each thread handles n = n0+(t&31), c = 2*(t>>5) + 16j ----
    {
        const int tn = t & 31;
        const int c2 = (t >> 5) * 2;
        for (int cc = 0; cc < 512; cc += 16) {
            const int c = cc + c2;
            float v0 = feat[(size_t)c * NN + n0 + tn];
            float v1 = feat[(size_t)(c + 1) * NN + n0 + tn];
            __bf16 b0 = (__bf16)v0, b1 = (__bf16)v1;
            xb[(size_t)c * NN + n0 + tn]       = b0;
            xb[(size_t)(c + 1) * NN + n0 + tn] = b1;
            bf16x2 pk; pk[0] = b0; pk[1] = b1;
            *(bf16x2*)&xt[tn][c] = pk;        // 4B-aligned (c even, row 1040B)
        }
    }
    __syncthreads();
    // ---- compute ----
    const int w    = t >> 6;              // 0..3 ; h0 = 32w
    const int lane = t & 63;
    const int l16  = lane & 15;
    const int q    = lane >> 4;
    const int h0   = w * 32;
    f32x4 afj[2][2] = {};                 // fj  : [i=h-16tile][tt=n-16tile]
    f32x4 afi[2][2] = {};                 // finm: [i=n-16tile][tt=h-16tile]
    for (int k = 0; k < 512; k += 32) {
        bf16x8 ln[2], wj[2], wi[2];
        #pragma unroll
        for (int i = 0; i < 2; i++)
            ln[i] = *(const bf16x8*)&xt[16 * i + l16][k + q * 8];
        #pragma unroll
        for (int i = 0; i < 2; i++)
            wj[i] = load_f32x8_as_bf16(Wj + (h0 + 16 * i + l16) * 512 + k + q * 8);
        #pragma unroll
        for (int i = 0; i < 2; i++)
            wi[i] = load_f32x8_as_bf16(Wi + (h0 + 16 * i + l16) * 512 + k + q * 8);
        #pragma unroll
        for (int i = 0; i < 2; i++)
            #pragma unroll
            for (int tt = 0; tt < 2; tt++) {
                afj[i][tt] = __builtin_amdgcn_mfma_f32_16x16x32_bf16(wj[i], ln[tt], afj[i][tt], 0, 0, 0);
                afi[i][tt] = __builtin_amdgcn_mfma_f32_16x16x32_bf16(ln[i], wi[tt], afi[i][tt], 0, 0, 0);
            }
    }
    #pragma unroll
    for (int i = 0; i < 2; i++)
        #pragma unroll
        for (int tt = 0; tt < 2; tt++)
            #pragma unroll
            for (int r = 0; r < 4; r++) {
                {   // fj: h = h0+16i+q*4+r, n = n0+16tt+l16
                    int h = h0 + 16 * i + q * 4 + r;
                    int n = n0 + 16 * tt + l16;
                    fj[(size_t)h * NN + n] = (__bf16)(afj[i][tt][r] + bj[h]);
                }
                {   // finm: n = n0+16i+q*4+r, h = h0+16tt+l16
                    int n = n0 + 16 * i + q * 4 + r;
                    int h = h0 + 16 * tt + l16;
                    finm[(size_t)n * HS + h] = (__bf16)(afi[i][tt][r] + bi[h]);
                }
            }
}

// ---------------------------------------------------------------------------
// K3 (G3): Mtf[c][h] += sum_n xb[c][n] * fj[h][n]   (fp32 atomics)
//   512 blocks x 256 thr: 64 tiles (32c x 32h) x 8 chunk-groups; 4 waves of a
//   block take 4 adjacent K-chunks (~10 ksteps), LDS-reduce, 8-way atomicAdd.
//   A now reads bf16 xb directly (half the bytes of fp32 feat, no cvt).
// ---------------------------------------------------------------------------
__global__ void k_gemm3(const __bf16* __restrict__ xb, const __bf16* __restrict__ fj,
                        float* __restrict__ Mtf) {
    __shared__ float red[4][64][17];
    const int b    = blockIdx.x;
    const int t    = threadIdx.x;
    const int v    = t >> 6;
    const int lane = t & 63;
    const int l16  = lane & 15;
    const int q    = lane >> 4;
    const int tile = b & 63, g = b >> 6;
    const int c0 = (tile >> 2) * 32, h0 = (tile & 3) * 32;
    const int chunk = g * 4 + v;
    const int s0 = (chunk * 324) >> 5;
    const int s1 = ((chunk + 1) * 324) >> 5;
    f32x4 acc[2][2] = {};
    for (int s = s0; s < s1; s++) {
        int k = s * 32;
        bf16x8 a[2], bb[2];
        #pragma unroll
        for (int i = 0; i < 2; i++)
            a[i] = *(const bf16x8*)(xb + (size_t)(c0 + 16 * i + l16) * NN + k + q * 8);
        #pragma unroll
        for (int tt = 0; tt < 2; tt++)
            bb[tt] = *(const bf16x8*)(fj + (size_t)(h0 + 16 * tt + l16) * NN + k + q * 8);
        #pragma unroll
        for (int i = 0; i < 2; i++)
            #pragma unroll
            for (int tt = 0; tt < 2; tt++)
                acc[i][tt] = __builtin_amdgcn_mfma_f32_16x16x32_bf16(a[i], bb[tt], acc[i][tt], 0, 0, 0);
    }
    #pragma unroll
    for (int i = 0; i < 2; i++)
        #pragma unroll
        for (int tt = 0; tt < 2; tt++)
            #pragma unroll
            for (int r = 0; r < 4; r++)
                red[v][lane][i * 8 + tt * 4 + r] = acc[i][tt][r];
    __syncthreads();
    #pragma unroll
    for (int u = 0; u < 4; u++) {
        const int idx = t * 4 + u;
        const int lane_e = idx >> 4, j = idx & 15;
        float s = red[0][lane_e][j] + red[1][lane_e][j]
                + red[2][lane_e][j] + red[3][lane_e][j];
        const int i = j >> 3, tt = (j >> 2) & 1, r = j & 3;
        const int qe = lane_e >> 4, le = lane_e & 15;
        const int c = c0 + 16 * i + qe * 4 + r;
        const int h = h0 + 16 * tt + le;
        atomicAdd(&Mtf[c * HS + h], s);
    }
}

// ---------------------------------------------------------------------------
// K4 (G4 + scale + residual):
//   out[c][n] = feat[c][n] + (agg/N) * sum_h Mtf[c][h] * finm[n][h]
//   A-fragments from fp32 Mtf (2x f32x4 + cvt), Bt = finm bf16, K=128.
//   Residual read stays fp32 feat (exact).
// ---------------------------------------------------------------------------
__global__ void k_gemm4(const float* __restrict__ Mtf, const __bf16* __restrict__ finm,
                        const float* __restrict__ feat, const float* __restrict__ agg,
                        float* __restrict__ out) {
    const int w    = blockIdx.x * 4 + (threadIdx.x >> 6);   // 0..2591
    const int lane = threadIdx.x & 63;
    const int l16  = lane & 15;
    const int q    = lane >> 4;
    const int c0 = (w & 15) * 32, n0 = (w >> 4) * 64;
    const float scale = agg[0] * (1.0f / (float)NN);
    f32x4 acc[2][4] = {};
    for (int k = 0; k < 128; k += 32) {
        bf16x8 a[2], b[4];
        #pragma unroll
        for (int i = 0; i < 2; i++)
            a[i] = load_f32x8_as_bf16(Mtf + (c0 + 16 * i + l16) * HS + k + q * 8);
        #pragma unroll
        for (int tt = 0; tt < 4; tt++)
            b[tt] = *(const bf16x8*)(finm + (size_t)(n0 + 16 * tt + l16) * HS + k + q * 8);
        #pragma unroll
        for (int i = 0; i < 2; i++)
            #pragma unroll
            for (int tt = 0; tt < 4; tt++)
                acc[i][tt] = __builtin_amdgcn_mfma_f32_16x16x32_bf16(a[i], b[tt], acc[i][tt], 0, 0, 0);
    }
    #pragma unroll
    for (int i = 0; i < 2; i++)
        #pragma unroll
        for (int tt = 0; tt < 4; tt++)
            #pragma unroll
            for (int r = 0; r < 4; r++) {
                int c = c0 + 16 * i + q * 4 + r;
                int n = n0 + 16 * tt + l16;
                size_t idx = (size_t)c * NN + n;
                out[idx] = feat[idx] + scale * acc[i][tt][r];
            }
}

// ---------------------------------------------------------------------------
// Workspace layout (bytes):
//   xb   @ 0          : 10,616,832
//   fj   @ 10,616,832 : 2,654,208
//   finm @ 13,271,040 : 2,654,208
//   Mtf  @ 15,925,248 : 262,144       total ~16.2 MB
// ---------------------------------------------------------------------------
extern "C" void kernel_launch(void* const* d_in, const int* in_sizes, int n_in,
                              void* d_out, int out_size, void* d_ws, size_t ws_size,
                              hipStream_t stream) {
    const float* feat = (const float*)d_in[0];
    const float* Wi   = (const float*)d_in[1];
    const float* bi   = (const float*)d_in[2];
    const float* Wj   = (const float*)d_in[3];
    const float* bj   = (const float*)d_in[4];
    const float* agg  = (const float*)d_in[5];
    float* out = (float*)d_out;

    char* ws = (char*)d_ws;
    __bf16* xb   = (__bf16*)(ws);
    __bf16* fj   = (__bf16*)(ws + 10616832);
    __bf16* finm = (__bf16*)(ws + 13271040);
    float*  Mtf  = (float*) (ws + 15925248);

    k_fused12<<<340, 256, 0, stream>>>(feat, Wi, Wj, bi, bj, xb, fj, finm, Mtf);
    k_gemm3<<<512, 256, 0, stream>>>(xb, fj, Mtf);
    k_gemm4<<<648, 256, 0, stream>>>(Mtf, finm, feat, agg, out);
}